// Round 12
// baseline (151.555 us; speedup 1.0000x reference)
//
#include <hip/hip_runtime.h>
#include <hip/hip_bf16.h>
#include <stdint.h>

// Problem constants (fixed by the reference)
#define NE      1048576     // edges
#define NNODES  65536       // B*N
#define DIMV    64          // embedding dim
#define HDIM    256         // SwiGLU hidden width

typedef __bf16 bf16x8 __attribute__((ext_vector_type(8)));
typedef float  f32x4  __attribute__((ext_vector_type(4)));
typedef float  f32x2  __attribute__((ext_vector_type(2)));

__device__ __forceinline__ unsigned short f2bf(float f) {
    union { float f; uint32_t u; } v; v.f = f;
    return (unsigned short)((v.u + 0x7fffu + ((v.u >> 16) & 1u)) >> 16);  // RNE
}

// ---------------- prep 1: node features fp32 -> bf16 table ----------------
__global__ void prep_x_kernel(const float* __restrict__ x, unsigned short* __restrict__ xb) {
    int i = blockIdx.x * blockDim.x + threadIdx.x;
    const int total = NNODES * DIMV / 4;
    for (; i < total; i += gridDim.x * blockDim.x) {
        float4 v = ((const float4*)x)[i];
        ushort4 o;
        o.x = f2bf(v.x); o.y = f2bf(v.y); o.z = f2bf(v.z); o.w = f2bf(v.w);
        ((ushort4*)xb)[i] = o;
    }
}

// ------- prep 2: weights -> transposed, XOR-swizzled bf16 images -------
// Per matrix 65536 B: column h (0..255), 16B chunk cc (0..15) holding W[k][h]
// for k = cc*8..cc*8+7, at byte h*256 + ((cc*16) ^ ((h&7)<<4)).
// w_out is folded into Wi: wi'[k][h] = wi[k][h] * wo[h].
__global__ void prep_w_kernel(const float* __restrict__ wg, const float* __restrict__ wi,
                              const float* __restrict__ wo, unsigned short* __restrict__ img) {
    int t = blockIdx.x * blockDim.x + threadIdx.x;
    if (t >= 2 * HDIM * 16) return;
    int mat = t >> 12;
    int h   = (t >> 4) & 255;
    int cc  = t & 15;
    const float* w = mat ? wi : wg;
    float scale = mat ? wo[h] : 1.0f;
    unsigned short tmp[8] __attribute__((aligned(16)));
    #pragma unroll
    for (int j = 0; j < 8; ++j)
        tmp[j] = f2bf(w[(cc * 8 + j) * HDIM + h] * scale);
    int byteoff = mat * 65536 + h * 256 + ((cc * 16) ^ ((h & 7) << 4));
    *(uint4*)((char*)img + byteoff) = *(const uint4*)tmp;
}

// ---------------- main: swapped-operand, per-nh 4-chain MFMA ----------------
// EXACT R9 shell (passed): 512 threads (8 waves), 512 edges = 4 tiles x 128,
// dbuf LDS staging, 1 barrier/tile, block-end combine. ONLY change: within each
// nh (hidden-unit group — silu is per-h, so nh accumulators must stay separate!),
// each accumulator splits by ks-parity into two independent chains, merged by
// packed adds BEFORE the nonlinearity. Same math as R9, 2x MFMA issue distance.
#define EDGES_PER_TILE 128
#define TILES 4
#define EDGES_PER_BLOCK (EDGES_PER_TILE * TILES)   // 512
__global__ __launch_bounds__(512)
void edge_swiglu_kernel(
    const unsigned short* __restrict__ xb,
    const unsigned short* __restrict__ wimg,
    const int* __restrict__ eidx,
    float* __restrict__ out)
{
    __shared__ char  alds[2][EDGES_PER_TILE * 256];   // 2 x 32 KiB staged features
    __shared__ float plds[8][EDGES_PER_BLOCK];        // 16 KiB per-wave partials

    const int tid  = threadIdx.x;
    const int lane = tid & 63;
    const int wave = tid >> 6;
    const int r = lane & 15;       // edge-within-frag / h-within-16 selector
    const int q = lane >> 4;       // k-group selector
    const int eb = blockIdx.x * EDGES_PER_BLOCK;

    // ---- prefetch ALL node indices to registers (4 chunks/thread/tile) ----
    int nodes[TILES][4];
    #pragma unroll
    for (int t = 0; t < TILES; ++t) {
        #pragma unroll
        for (int i = 0; i < 4; ++i) {
            int idx = i * 512 + tid;
            int el  = idx >> 4;
            int c   = idx & 15;
            int e   = eb + t * EDGES_PER_TILE + el;
            nodes[t][i] = (c & 8) ? eidx[NE + e] : eidx[e];
        }
    }

    // ---- W^T fragments into registers: wave's 32-h slice (loaded once) ----
    // A-operand layout (16x16x32): row = lane&15 = h-within-16, k = q*8+j.
    bf16x8 bw[2][2][4];   // [nh][mat][ks]
    #pragma unroll
    for (int nh = 0; nh < 2; ++nh) {
        int h      = (wave * 2 + nh) * 16 + r;
        int rowoff = h << 8;
        int swz    = (h & 7) << 4;
        #pragma unroll
        for (int mat = 0; mat < 2; ++mat) {
            #pragma unroll
            for (int ks = 0; ks < 4; ++ks) {
                int cb = ((4 * ks + q) * 16) ^ swz;
                bw[nh][mat][ks] = *(const bf16x8*)((const char*)wimg + mat * 65536 + rowoff + cb);
            }
        }
    }

    // ---- stage tile 0 -> buf 0 ----
    // LDS slot (el, c) holds node-half (c>>3), source chunk (c&7)^(el&7); dest linear.
    #pragma unroll
    for (int i = 0; i < 4; ++i) {
        int idx  = i * 512 + tid;
        int el   = idx >> 4;
        int c    = idx & 15;
        int srcc = (c & 7) ^ (el & 7);
        const unsigned short* src = xb + nodes[0][i] * 64 + srcc * 8;
        __builtin_amdgcn_global_load_lds(
            (const __attribute__((address_space(1))) void*)src,
            (__attribute__((address_space(3))) void*)(alds[0] + idx * 16),
            16, 0, 0);
    }

    #pragma unroll
    for (int t = 0; t < TILES; ++t) {
        // ONE barrier per tile: proves stage(t) landed (vmcnt drained per-wave
        // before s_barrier) and buf[(t+1)&1]'s prior readers finished.
        __syncthreads();

        if (t + 1 < TILES) {
            #pragma unroll
            for (int i = 0; i < 4; ++i) {
                int idx  = i * 512 + tid;
                int el   = idx >> 4;
                int c    = idx & 15;
                int srcc = (c & 7) ^ (el & 7);
                const unsigned short* src = xb + nodes[t + 1][i] * 64 + srcc * 8;
                __builtin_amdgcn_global_load_lds(
                    (const __attribute__((address_space(1))) void*)src,
                    (__attribute__((address_space(3))) void*)(alds[(t + 1) & 1] + idx * 16),
                    16, 0, 0);
            }
        }

        // ---- compute tile t ----
        const char* abuf = alds[t & 1];
        #pragma unroll
        for (int mf = 0; mf < EDGES_PER_TILE / 16; ++mf) {
            const int   el   = mf * 16 + r;
            const char* arow = abuf + el * 256;

            // X-frags (B-operand): col = lane&15 = edge, k = q*8+j per ks-tile.
            // chunk ck = 4*ks+q; LDS slot c = (ck&8) | ((ck&7) ^ (r&7)).
            bf16x8 x[4];
            #pragma unroll
            for (int ks = 0; ks < 4; ++ks) {
                int ck = 4 * ks + q;
                int c  = (ck & 8) | ((ck & 7) ^ (r & 7));
                x[ks] = *(const bf16x8*)(arow + c * 16);
            }

            f32x2 part2 = {0.0f, 0.0f};
            #pragma unroll
            for (int nh = 0; nh < 2; ++nh) {
                // 4 independent chains WITHIN this nh (a: ks 0,2; b: ks 1,3),
                // merged before silu. Accumulators never cross nh (silu is per-h).
                f32x4 aGa = {0.0f, 0.0f, 0.0f, 0.0f};
                f32x4 aGb = {0.0f, 0.0f, 0.0f, 0.0f};
                f32x4 aIa = {0.0f, 0.0f, 0.0f, 0.0f};
                f32x4 aIb = {0.0f, 0.0f, 0.0f, 0.0f};
                __builtin_amdgcn_s_setprio(1);
                aGa = __builtin_amdgcn_mfma_f32_16x16x32_bf16(bw[nh][0][0], x[0], aGa, 0, 0, 0);
                aIa = __builtin_amdgcn_mfma_f32_16x16x32_bf16(bw[nh][1][0], x[0], aIa, 0, 0, 0);
                aGb = __builtin_amdgcn_mfma_f32_16x16x32_bf16(bw[nh][0][1], x[1], aGb, 0, 0, 0);
                aIb = __builtin_amdgcn_mfma_f32_16x16x32_bf16(bw[nh][1][1], x[1], aIb, 0, 0, 0);
                aGa = __builtin_amdgcn_mfma_f32_16x16x32_bf16(bw[nh][0][2], x[2], aGa, 0, 0, 0);
                aIa = __builtin_amdgcn_mfma_f32_16x16x32_bf16(bw[nh][1][2], x[2], aIa, 0, 0, 0);
                aGb = __builtin_amdgcn_mfma_f32_16x16x32_bf16(bw[nh][0][3], x[3], aGb, 0, 0, 0);
                aIb = __builtin_amdgcn_mfma_f32_16x16x32_bf16(bw[nh][1][3], x[3], aIb, 0, 0, 0);
                __builtin_amdgcn_s_setprio(0);

                // merge chains (packed adds), then silu(g)*i', in-lane sum
                #pragma unroll
                for (int jj = 0; jj < 2; ++jj) {
                    f32x2 g  = (f32x2){aGa[2 * jj], aGa[2 * jj + 1]}
                             + (f32x2){aGb[2 * jj], aGb[2 * jj + 1]};
                    f32x2 iv = (f32x2){aIa[2 * jj], aIa[2 * jj + 1]}
                             + (f32x2){aIb[2 * jj], aIb[2 * jj + 1]};
                    f32x2 tt = g * (f32x2){-1.44269504f, -1.44269504f};
                    f32x2 ex = {__builtin_amdgcn_exp2f(tt[0]), __builtin_amdgcn_exp2f(tt[1])};
                    f32x2 d  = ex + (f32x2){1.0f, 1.0f};
                    f32x2 rc = {__builtin_amdgcn_rcpf(d[0]), __builtin_amdgcn_rcpf(d[1])};
                    part2 += (g * iv) * rc;
                }
            }
            float part = part2[0] + part2[1];
            // sum over q-groups (h-quarters): lanes differing in bits 4,5
            part += __shfl_xor(part, 16);
            part += __shfl_xor(part, 32);
            if (lane < 16) plds[wave][t * EDGES_PER_TILE + mf * 16 + lane] = part;
        }
    }

    __syncthreads();   // plds complete

    // ---- combine the 8 wave partials per edge ONCE, coalesced store ----
    {
        float s = 0.0f;
        #pragma unroll
        for (int w = 0; w < 8; ++w) s += plds[w][tid];
        out[eb + tid] = s;
    }
}

extern "C" void kernel_launch(void* const* d_in, const int* in_sizes, int n_in,
                              void* d_out, int out_size, void* d_ws, size_t ws_size,
                              hipStream_t stream) {
    const float* x   = (const float*)d_in[0];   // [65536, 64] fp32
    const float* wg  = (const float*)d_in[1];   // [128, 256] fp32
    const float* wi  = (const float*)d_in[2];   // [128, 256] fp32
    const float* wo  = (const float*)d_in[3];   // [256] fp32
    const int*   ei  = (const int*)d_in[4];     // [2, E] int
    float* out = (float*)d_out;

    unsigned short* xb   = (unsigned short*)d_ws;                       // 8 MiB bf16 node table
    unsigned short* wimg = (unsigned short*)((char*)d_ws + 8388608);    // 128 KiB weight images

    prep_x_kernel<<<1024, 256, 0, stream>>>(x, xb);
    prep_w_kernel<<<32, 256, 0, stream>>>(wg, wi, wo, wimg);
    edge_swiglu_kernel<<<NE / EDGES_PER_BLOCK, 512, 0, stream>>>(xb, wimg, ei, out);
}

// Round 13
// 140.410 us; speedup vs baseline: 1.0794x; 1.0794x over previous
//
#include <hip/hip_runtime.h>
#include <hip/hip_bf16.h>
#include <stdint.h>

// Problem constants (fixed by the reference)
#define NE      1048576     // edges
#define NNODES  65536       // B*N
#define DIMV    64          // embedding dim
#define HDIM    256         // SwiGLU hidden width

typedef __bf16 bf16x8 __attribute__((ext_vector_type(8)));
typedef float  f32x4  __attribute__((ext_vector_type(4)));

__device__ __forceinline__ unsigned short f2bf(float f) {
    union { float f; uint32_t u; } v; v.f = f;
    return (unsigned short)((v.u + 0x7fffu + ((v.u >> 16) & 1u)) >> 16);  // RNE
}

// lane[i] += lane[i^16] via v_permlane16_swap_b32 (VALU) instead of ds_bpermute
__device__ __forceinline__ float swap16_add(float x) {
#if __has_builtin(__builtin_amdgcn_permlane16_swap)
    int xi = __float_as_int(x);
    auto rr = __builtin_amdgcn_permlane16_swap(xi, xi, false, false);
    return __int_as_float(rr[0]) + __int_as_float(rr[1]);
#else
    return x + __shfl_xor(x, 16);
#endif
}

// lane[i] += lane[i^32] via v_permlane32_swap_b32 (VALU)
__device__ __forceinline__ float swap32_add(float x) {
#if __has_builtin(__builtin_amdgcn_permlane32_swap)
    int xi = __float_as_int(x);
    auto rr = __builtin_amdgcn_permlane32_swap(xi, xi, false, false);
    return __int_as_float(rr[0]) + __int_as_float(rr[1]);
#else
    return x + __shfl_xor(x, 32);
#endif
}

// ---------------- prep 1: node features fp32 -> bf16 table ----------------
__global__ void prep_x_kernel(const float* __restrict__ x, unsigned short* __restrict__ xb) {
    int i = blockIdx.x * blockDim.x + threadIdx.x;
    const int total = NNODES * DIMV / 4;
    for (; i < total; i += gridDim.x * blockDim.x) {
        float4 v = ((const float4*)x)[i];
        ushort4 o;
        o.x = f2bf(v.x); o.y = f2bf(v.y); o.z = f2bf(v.z); o.w = f2bf(v.w);
        ((ushort4*)xb)[i] = o;
    }
}

// ------- prep 2: weights -> transposed, XOR-swizzled bf16 images -------
// Per matrix 65536 B: column h (0..255), 16B chunk cc (0..15) holding W[k][h]
// for k = cc*8..cc*8+7, at byte h*256 + ((cc*16) ^ ((h&7)<<4)).
// w_out is folded into Wi: wi'[k][h] = wi[k][h] * wo[h].
__global__ void prep_w_kernel(const float* __restrict__ wg, const float* __restrict__ wi,
                              const float* __restrict__ wo, unsigned short* __restrict__ img) {
    int t = blockIdx.x * blockDim.x + threadIdx.x;
    if (t >= 2 * HDIM * 16) return;
    int mat = t >> 12;
    int h   = (t >> 4) & 255;
    int cc  = t & 15;
    const float* w = mat ? wi : wg;
    float scale = mat ? wo[h] : 1.0f;
    unsigned short tmp[8] __attribute__((aligned(16)));
    #pragma unroll
    for (int j = 0; j < 8; ++j)
        tmp[j] = f2bf(w[(cc * 8 + j) * HDIM + h] * scale);
    int byteoff = mat * 65536 + h * 256 + ((cc * 16) ^ ((h & 7) << 4));
    *(uint4*)((char*)img + byteoff) = *(const uint4*)tmp;
}

// ---------------- main: swapped-operand fused kernel (R6 champion shell) ----------------
// Block = 512 threads (8 waves), 256 edges. Wave w owns h-slice [32w, 32w+32)
// with its W^T fragments resident in 64 AGPR-backed regs (loaded once).
// Block stages 256 edges x 256B gathered features into 64KB LDS ONCE via
// global_load_lds; all 8 waves share them. D[h,e] layout -> h-reduction in-lane;
// ONLY change vs R6: the q-group reduction uses permlane16/32_swap (VALU,
// ~4-8 cyc) instead of two ds_bpermute shuffles (~120 cyc LDS latency each).
#define EDGES_PER_BLOCK 256
__global__ __launch_bounds__(512)
void edge_swiglu_kernel(
    const unsigned short* __restrict__ xb,
    const unsigned short* __restrict__ wimg,
    const int* __restrict__ eidx,
    float* __restrict__ out)
{
    __shared__ char  alds[EDGES_PER_BLOCK * 256];   // 64 KiB gathered features
    __shared__ float plds[8][EDGES_PER_BLOCK];      // 8 KiB per-wave partials

    const int tid  = threadIdx.x;
    const int lane = tid & 63;
    const int wave = tid >> 6;
    const int r = lane & 15;       // A-row (h) / B-col (edge) lane selector
    const int q = lane >> 4;       // k-group selector
    const int eb = blockIdx.x * EDGES_PER_BLOCK;

    // ---- stage gathered edge features -> LDS (issue first; latency hides
    // under the W-register loads below). chunk idx: el = idx>>4, c = idx&15.
    // LDS slot (el, c) holds node-half (c>>3), source chunk (c&7)^(el&7).
    #pragma unroll
    for (int i = 0; i < 8; ++i) {
        int idx  = i * 512 + tid;
        int el   = idx >> 4;
        int c    = idx & 15;
        int half = c >> 3;
        int srcc = (c & 7) ^ (el & 7);
        int e    = eb + el;
        int node = half ? eidx[NE + e] : eidx[e];
        const unsigned short* src = xb + node * 64 + srcc * 8;
        __builtin_amdgcn_global_load_lds(
            (const __attribute__((address_space(1))) void*)src,
            (__attribute__((address_space(3))) void*)(alds + idx * 16),
            16, 0, 0);
    }

    // ---- W^T fragments into registers: wave's 32-h slice (nf = 2*wave+nh)
    // A-operand layout (16x16x32): row = lane&15 = h-within-16, k = q*8+j.
    bf16x8 bw[2][2][4];   // [nh][mat][ks]
    #pragma unroll
    for (int nh = 0; nh < 2; ++nh) {
        int h      = (wave * 2 + nh) * 16 + r;
        int rowoff = h << 8;
        int swz    = (h & 7) << 4;
        #pragma unroll
        for (int mat = 0; mat < 2; ++mat) {
            #pragma unroll
            for (int ks = 0; ks < 4; ++ks) {
                int cb = ((4 * ks + q) * 16) ^ swz;
                bw[nh][mat][ks] = *(const bf16x8*)((const char*)wimg + mat * 65536 + rowoff + cb);
            }
        }
    }

    __syncthreads();   // barrier drains vmcnt -> staged A complete

    // ---- main loop: 16 M-frags of 16 edges
    #pragma unroll 2
    for (int mf = 0; mf < 16; ++mf) {
        const int   el   = mf * 16 + r;
        const char* arow = alds + el * 256;

        // X-frags (B-operand): col = lane&15 = edge, k = q*8+j per ks-tile.
        // chunk ck = 4*ks+q; LDS slot c = (ck&8) | ((ck&7) ^ (r&7)).
        bf16x8 x[4];
        #pragma unroll
        for (int ks = 0; ks < 4; ++ks) {
            int ck = 4 * ks + q;
            int c  = (ck & 8) | ((ck & 7) ^ (r & 7));
            x[ks] = *(const bf16x8*)(arow + c * 16);
        }

        float part = 0.0f;
        #pragma unroll
        for (int nh = 0; nh < 2; ++nh) {
            f32x4 aG = {0.0f, 0.0f, 0.0f, 0.0f};
            f32x4 aI = {0.0f, 0.0f, 0.0f, 0.0f};
            #pragma unroll
            for (int ks = 0; ks < 4; ++ks) {
                aG = __builtin_amdgcn_mfma_f32_16x16x32_bf16(bw[nh][0][ks], x[ks], aG, 0, 0, 0);
                aI = __builtin_amdgcn_mfma_f32_16x16x32_bf16(bw[nh][1][ks], x[ks], aI, 0, 0, 0);
            }
            // D[h,e]: lane holds h = nf*16 + q*4 + j for edge el -> in-lane sum
            #pragma unroll
            for (int j = 0; j < 4; ++j) {
                float g  = aG[j];
                float iv = aI[j];
                float e2 = __builtin_amdgcn_exp2f(g * -1.44269504f);
                float s  = __builtin_amdgcn_rcpf(1.0f + e2);
                part = __builtin_fmaf(g * s, iv, part);
            }
        }
        // sum over q-groups (h-quarters) with permlane swaps (pure VALU)
        part = swap16_add(part);
        part = swap32_add(part);
        if (lane < 16) plds[wave][mf * 16 + lane] = part;
    }

    __syncthreads();

    // ---- combine the 8 wave partials per edge, coalesced store
    if (tid < EDGES_PER_BLOCK) {
        float s = 0.0f;
        #pragma unroll
        for (int w = 0; w < 8; ++w) s += plds[w][tid];
        out[eb + tid] = s;
    }
}

extern "C" void kernel_launch(void* const* d_in, const int* in_sizes, int n_in,
                              void* d_out, int out_size, void* d_ws, size_t ws_size,
                              hipStream_t stream) {
    const float* x   = (const float*)d_in[0];   // [65536, 64] fp32
    const float* wg  = (const float*)d_in[1];   // [128, 256] fp32
    const float* wi  = (const float*)d_in[2];   // [128, 256] fp32
    const float* wo  = (const float*)d_in[3];   // [256] fp32
    const int*   ei  = (const int*)d_in[4];     // [2, E] int
    float* out = (float*)d_out;

    unsigned short* xb   = (unsigned short*)d_ws;                       // 8 MiB bf16 node table
    unsigned short* wimg = (unsigned short*)((char*)d_ws + 8388608);    // 128 KiB weight images

    prep_x_kernel<<<1024, 256, 0, stream>>>(x, xb);
    prep_w_kernel<<<32, 256, 0, stream>>>(wg, wi, wo, wimg);
    edge_swiglu_kernel<<<NE / EDGES_PER_BLOCK, 512, 0, stream>>>(xb, wimg, ei, out);
}